// Round 8
// baseline (175.028 us; speedup 1.0000x reference)
//
#include <hip/hip_runtime.h>

#define RR 12
#define PD 25
#define PP 625
#define HH 30
#define WW 30
#define HWD 900
#define CD 512
#define BD 8
#define TD 4
#define CSTRIDE 628           // 625 + 3 pad
#define ROWPK 32768           // shorts per packed (plane,row): 32ks * 2hl * 64lane * 8

typedef __attribute__((ext_vector_type(8))) short bf16x8;
typedef __attribute__((ext_vector_type(16))) float f32x16;

__device__ __forceinline__ unsigned short f2bf_rn(float x) {
    unsigned int u = __float_as_uint(x);
    u += 0x7fffu + ((u >> 16) & 1u);
    return (unsigned short)(u >> 16);
}

// relu + L2-normalize over C, then write hi/lo split-bf16 directly in
// 32x32x16-MFMA fragment-major layout: [plane][row][ks][hl][lane][8]
// element (pix x = lane&31, k = ks*16 + (lane>>5)*8 + j)
__global__ __launch_bounds__(256) void norm_pack_kernel(const float* __restrict__ in,
                                                        unsigned short* __restrict__ outp,
                                                        int c_stride, int t_count) {
    int row = blockIdx.x;    // y (or h), 0..29
    int plane = blockIdx.y;
    int b = plane / t_count;
    int t = plane - b * t_count;
    size_t base = (size_t)b * CD * c_stride + (size_t)t * HWD + row * WW;
    __shared__ float tile[30][516];
    __shared__ float inv[30];
    int tid = threadIdx.x;
    for (int it = 0; it < 64; ++it) {
        int lin = it * 256 + tid;
        int c = lin >> 5, p = lin & 31;
        if (p < 30) tile[p][c] = fmaxf(in[base + (size_t)c * c_stride + p], 0.f);
    }
    __syncthreads();
    if ((tid >> 3) < 30) {
        int p = tid >> 3, s8 = tid & 7;
        float acc = 0.f;
#pragma unroll
        for (int j = 0; j < 16; ++j) {
            const float4 v = *reinterpret_cast<const float4*>(&tile[p][(s8 + j * 8) * 4]);
            acc += v.x * v.x + v.y * v.y + v.z * v.z + v.w * v.w;
        }
        acc += __shfl_xor(acc, 1);
        acc += __shfl_xor(acc, 2);
        acc += __shfl_xor(acc, 4);
        if (s8 == 0) inv[p] = 1.0f / fmaxf(sqrtf(acc), 1e-12f);
    }
    __syncthreads();
    unsigned short* ob = outp + (size_t)(plane * 30 + row) * ROWPK;
    for (int sl = tid; sl < 2048; sl += 256) {   // sl = ks*64 + lane
        int ks = sl >> 6, ln = sl & 63;
        int x = ln & 31;
        if (x > 29) x = 29;                       // pad lanes (guarded in corr)
        int kb = ks * 16 + (ln >> 5) * 8;
        float iv = inv[x];
        bf16x8 hv, lv;
#pragma unroll
        for (int j = 0; j < 8; ++j) {
            float nv = tile[x][kb + j] * iv;
            unsigned short hs = f2bf_rn(nv);
            float hf = __uint_as_float((unsigned int)hs << 16);
            hv[j] = (short)hs;
            lv[j] = (short)f2bf_rn(nv - hf);
        }
        *(bf16x8*)(ob + (size_t)(ks * 2 + 0) * 512 + ln * 8) = hv;
        *(bf16x8*)(ob + (size_t)(ks * 2 + 1) * 512 + ln * 8) = lv;
    }
}

// 1D grid of 960, XCD-bijective swizzle: xcd r owns b=r (bt in 4r..4r+3, h-major).
// 768 thr = 12 waves; wave owns dh PAIRS (A-fragments shared across the pair,
// 6 MFMA chains). A-row staged in LDS once; 32x32x16 MFMA, 3-chain split-bf16.
__global__ __launch_bounds__(768, 3) void corr_kernel(
    const unsigned short* __restrict__ Apk, const unsigned short* __restrict__ Bpk,
    float* __restrict__ out) {
    int gid = blockIdx.x;
    int r = gid & 7;          // target XCD
    int x_ = gid >> 3;        // 0..119
    int btl = x_ / 30;
    int h = x_ - btl * 30;
    int bt = r * 4 + btl;
    int b = r;

    __shared__ float corr[HH * CSTRIDE];
    __shared__ unsigned short alds[ROWPK];
    __shared__ float is_lds[HH];
    int tid = threadIdx.x;
    int wid = tid >> 6, lane = tid & 63;

    for (int i = tid; i < HH * CSTRIDE; i += 768) corr[i] = 0.f;
    // stage A row (64 KB) into LDS, linear copy
    {
        const uint4* src = (const uint4*)(Apk + (size_t)(b * 30 + h) * ROWPK);
        uint4* dst = (uint4*)alds;
        for (int i = tid; i < 4096; i += 768) dst[i] = src[i];
    }
    const unsigned short* bplane = Bpk + (size_t)bt * 30 * ROWPK + lane * 8;
    int dh_lo = max(0, RR - h);
    int dh_hi = min(PD - 1, HH - 1 + RR - h);
    int npairs = (dh_hi - dh_lo + 2) >> 1;
    __syncthreads();  // corr zeroed + A staged

    const unsigned short* albase = alds + lane * 8;
    for (int p = wid; p < npairs; p += 12) {
        int dh1 = dh_lo + 2 * p;
        int dh2 = dh1 + 1;
        bool v2 = (dh2 <= dh_hi);
        int y1 = h + dh1 - RR;
        int y2 = v2 ? (y1 + 1) : y1;
        const unsigned short* bb1 = bplane + (size_t)y1 * ROWPK;
        const unsigned short* bb2 = bplane + (size_t)y2 * ROWPK;
        f32x16 acc1a = {0}, acc1b = {0}, acc1c = {0};
        f32x16 acc2a = {0}, acc2b = {0}, acc2c = {0};
#pragma unroll
        for (int i = 0; i < 16; ++i) {
            acc1a[i] = 0.f; acc1b[i] = 0.f; acc1c[i] = 0.f;
            acc2a[i] = 0.f; acc2b[i] = 0.f; acc2c[i] = 0.f;
        }
#pragma unroll 4
        for (int ks = 0; ks < 32; ++ks) {
            bf16x8 aH = *(const bf16x8*)(albase + ks * 1024);
            bf16x8 aL = *(const bf16x8*)(albase + ks * 1024 + 512);
            bf16x8 bH1 = *(const bf16x8*)(bb1 + ks * 1024);
            bf16x8 bL1 = *(const bf16x8*)(bb1 + ks * 1024 + 512);
            bf16x8 bH2 = *(const bf16x8*)(bb2 + ks * 1024);
            bf16x8 bL2 = *(const bf16x8*)(bb2 + ks * 1024 + 512);
            acc1a = __builtin_amdgcn_mfma_f32_32x32x16_bf16(aH, bH1, acc1a, 0, 0, 0);
            acc1b = __builtin_amdgcn_mfma_f32_32x32x16_bf16(aH, bL1, acc1b, 0, 0, 0);
            acc1c = __builtin_amdgcn_mfma_f32_32x32x16_bf16(aL, bH1, acc1c, 0, 0, 0);
            acc2a = __builtin_amdgcn_mfma_f32_32x32x16_bf16(aH, bH2, acc2a, 0, 0, 0);
            acc2b = __builtin_amdgcn_mfma_f32_32x32x16_bf16(aH, bL2, acc2b, 0, 0, 0);
            acc2c = __builtin_amdgcn_mfma_f32_32x32x16_bf16(aL, bH2, acc2c, 0, 0, 0);
        }
        int x = lane & 31;
        if (x < 30) {
            int rbase = 4 * (lane >> 5);
#pragma unroll
            for (int rr = 0; rr < 16; ++rr) {
                int w = (rr & 3) + 8 * (rr >> 2) + rbase;  // C layout: col=lane&31
                int dw = x - w + RR;
                if (w < 30 && (unsigned)dw < (unsigned)PD) {
                    corr[w * CSTRIDE + dh1 * PD + dw] = acc1a[rr] + acc1b[rr] + acc1c[rr];
                    if (v2)
                        corr[w * CSTRIDE + dh2 * PD + dw] = acc2a[rr] + acc2b[rr] + acc2c[rr];
                }
            }
        }
    }
    __syncthreads();

    // per-pixel softmax over 625 offsets (zeros present for OOB offsets)
    for (int w = wid; w < WW; w += 12) {
        float m = 0.f;
        for (int i = lane; i < PP; i += 64) m = fmaxf(m, corr[w * CSTRIDE + i]);
        m = fmaxf(m, __shfl_xor(m, 1));
        m = fmaxf(m, __shfl_xor(m, 2));
        m = fmaxf(m, __shfl_xor(m, 4));
        m = fmaxf(m, __shfl_xor(m, 8));
        m = fmaxf(m, __shfl_xor(m, 16));
        m = fmaxf(m, __shfl_xor(m, 32));
        float s = 0.f;
        for (int i = lane; i < PP; i += 64) {
            float e = __expf(512.f * (corr[w * CSTRIDE + i] - m));
            s += e;
            corr[w * CSTRIDE + i] = e;  // cache exp for write phase
        }
        s += __shfl_xor(s, 1);
        s += __shfl_xor(s, 2);
        s += __shfl_xor(s, 4);
        s += __shfl_xor(s, 8);
        s += __shfl_xor(s, 16);
        s += __shfl_xor(s, 32);
        if (lane == 0) is_lds[w] = 1.0f / s;
    }
    __syncthreads();

    // masked write: out[bt][i=dh*25+dw][h][w]
    float* obase = out + (size_t)bt * PP * HWD + h * WW;
    for (int idx = tid; idx < PP * WW; idx += 768) {
        int i = idx / 30;
        int w = idx - i * 30;
        int dh = i / 25, dw = i - dh * 25;
        bool valid = ((unsigned)(h + dh - RR) < (unsigned)HH) &&
                     ((unsigned)(w + dw - RR) < (unsigned)WW);
        float val = -1.0f;
        if (valid) val = corr[w * CSTRIDE + i] * is_lds[w];
        obase[(size_t)i * HWD + w] = val;
    }
}

extern "C" void kernel_launch(void* const* d_in, const int* in_sizes, int n_in,
                              void* d_out, int out_size, void* d_ws, size_t ws_size,
                              hipStream_t stream) {
    const float* feat1 = (const float*)d_in[0];  // video [8,512,4,30,30]
    const float* feat2 = (const float*)d_in[1];  // patch [8,512,30,30]
    float* out = (float*)d_out;
    unsigned short* Apk = (unsigned short*)d_ws;                 // [8*30][ROWPK]
    unsigned short* Bpk = Apk + (size_t)BD * 30 * ROWPK;         // [32*30][ROWPK]

    norm_pack_kernel<<<dim3(30, 8), 256, 0, stream>>>(feat2, Apk, HWD, 1);
    norm_pack_kernel<<<dim3(30, 32), 256, 0, stream>>>(feat1, Bpk, TD * HWD, TD);
    corr_kernel<<<dim3(960), 768, 0, stream>>>(Apk, Bpk, out);
}

// Round 9
// 119.841 us; speedup vs baseline: 1.4605x; 1.4605x over previous
//
#include <hip/hip_runtime.h>

#define RR 12
#define PD 25
#define PP 625
#define HH 30
#define WW 30
#define HWD 900
#define CD 512
#define BD 8
#define TD 4
#define CSTRIDE 628            // 625 + 3 pad
#define ROWPKB 32768           // BYTES per packed (plane,row): 16ks * 2piece * 64lane * 16B

typedef __attribute__((ext_vector_type(4))) int i32x4;
typedef __attribute__((ext_vector_type(16))) int i32x16;

// relu + L2-normalize over C, then quantize to 2-piece int8 fixed point:
//   a ~= (A1 + A2/254)/127,  A1 in [0,127], A2 in [-127,127]
// packed in 32x32x32-i8 MFMA fragment-major layout:
//   [plane][row][ks(16)][piece(2)][lane(64)][16 bytes]
//   element (pix x = lane&31, k = ks*32 + (lane>>5)*16 + j)
__global__ __launch_bounds__(256) void norm_pack_kernel(const float* __restrict__ in,
                                                        unsigned char* __restrict__ outp,
                                                        int c_stride, int t_count) {
    int row = blockIdx.x;    // y (or h), 0..29
    int plane = blockIdx.y;
    int b = plane / t_count;
    int t = plane - b * t_count;
    size_t base = (size_t)b * CD * c_stride + (size_t)t * HWD + row * WW;
    __shared__ float tile[30][516];
    __shared__ float inv[30];
    int tid = threadIdx.x;
    for (int it = 0; it < 64; ++it) {
        int lin = it * 256 + tid;
        int c = lin >> 5, p = lin & 31;
        if (p < 30) tile[p][c] = fmaxf(in[base + (size_t)c * c_stride + p], 0.f);
    }
    __syncthreads();
    if ((tid >> 3) < 30) {
        int p = tid >> 3, s8 = tid & 7;
        float acc = 0.f;
#pragma unroll
        for (int j = 0; j < 16; ++j) {
            const float4 v = *reinterpret_cast<const float4*>(&tile[p][(s8 + j * 8) * 4]);
            acc += v.x * v.x + v.y * v.y + v.z * v.z + v.w * v.w;
        }
        acc += __shfl_xor(acc, 1);
        acc += __shfl_xor(acc, 2);
        acc += __shfl_xor(acc, 4);
        if (s8 == 0) inv[p] = 1.0f / fmaxf(sqrtf(acc), 1e-12f);
    }
    __syncthreads();
    unsigned char* ob = outp + (size_t)(plane * 30 + row) * ROWPKB;
    for (int sl = tid; sl < 1024; sl += 256) {   // sl = ks*64 + lane
        int ks = sl >> 6, ln = sl & 63;
        int x = ln & 31;
        if (x > 29) x = 29;                       // pad lanes (guarded in corr)
        int kb = ks * 32 + (ln >> 5) * 16;
        float iv = inv[x];
        union { signed char c[16]; i32x4 v; } p1, p2;
#pragma unroll
        for (int j = 0; j < 16; ++j) {
            float nv = tile[x][kb + j] * iv;      // in [0,1]
            float s1 = rintf(nv * 127.f);
            float r = nv * 127.f - s1;
            float s2 = rintf(r * 254.f);
            p1.c[j] = (signed char)(int)s1;
            p2.c[j] = (signed char)(int)s2;
        }
        *(i32x4*)(ob + (size_t)ks * 2048 + ln * 16) = p1.v;
        *(i32x4*)(ob + (size_t)ks * 2048 + 1024 + ln * 16) = p2.v;
    }
}

// 1D grid of 960, XCD-bijective swizzle: xcd r owns b=r (bt in 4r..4r+3, h-major).
// 1024 thr = 16 waves; wave owns dh slots (stride 16). A-row staged in LDS (32 KB);
// B streamed from global (XCD-L2-local). v_mfma_i32_32x32x32_i8, 4 int chains.
__global__ __launch_bounds__(1024, 4) void corr_kernel(
    const unsigned char* __restrict__ Apk, const unsigned char* __restrict__ Bpk,
    float* __restrict__ out) {
    int gid = blockIdx.x;
    int r = gid & 7;          // target XCD
    int x_ = gid >> 3;        // 0..119
    int btl = x_ / 30;
    int h = x_ - btl * 30;
    int bt = r * 4 + btl;
    int b = r;

    __shared__ float corr[HH * CSTRIDE];
    __shared__ unsigned char alds[ROWPKB];
    __shared__ float is_lds[HH];
    int tid = threadIdx.x;
    int wid = tid >> 6, lane = tid & 63;

    for (int i = tid; i < HH * CSTRIDE; i += 1024) corr[i] = 0.f;
    // stage A row (32 KB) into LDS, linear copy
    {
        const uint4* src = (const uint4*)(Apk + (size_t)(b * 30 + h) * ROWPKB);
        uint4* dst = (uint4*)alds;
#pragma unroll
        for (int i = 0; i < 2; ++i) dst[i * 1024 + tid] = src[i * 1024 + tid];
    }
    const unsigned char* bplane = Bpk + (size_t)bt * 30 * ROWPKB + lane * 16;
    int dh_lo = max(0, RR - h);
    int dh_hi = min(PD - 1, HH - 1 + RR - h);
    __syncthreads();  // corr zeroed + A staged

    const unsigned char* albase = alds + lane * 16;
    for (int dh = dh_lo + wid; dh <= dh_hi; dh += 16) {
        int y = h + dh - RR;
        const unsigned char* bbase = bplane + (size_t)y * ROWPKB;
        i32x16 s11, s12, s21, s22;
#pragma unroll
        for (int i = 0; i < 16; ++i) { s11[i] = 0; s12[i] = 0; s21[i] = 0; s22[i] = 0; }
#pragma unroll 8
        for (int ks = 0; ks < 16; ++ks) {
            i32x4 a1 = *(const i32x4*)(albase + ks * 2048);
            i32x4 a2 = *(const i32x4*)(albase + ks * 2048 + 1024);
            i32x4 b1 = *(const i32x4*)(bbase + ks * 2048);
            i32x4 b2 = *(const i32x4*)(bbase + ks * 2048 + 1024);
            s11 = __builtin_amdgcn_mfma_i32_32x32x32_i8(a1, b1, s11, 0, 0, 0);
            s12 = __builtin_amdgcn_mfma_i32_32x32x32_i8(a1, b2, s12, 0, 0, 0);
            s21 = __builtin_amdgcn_mfma_i32_32x32x32_i8(a2, b1, s21, 0, 0, 0);
            s22 = __builtin_amdgcn_mfma_i32_32x32x32_i8(a2, b2, s22, 0, 0, 0);
        }
        int x = lane & 31;
        if (x < 30) {
            int rbase = 4 * (lane >> 5);
#pragma unroll
            for (int rr = 0; rr < 16; ++rr) {
                int w = (rr & 3) + 8 * (rr >> 2) + rbase;  // C layout: col=lane&31
                int dw = x - w + RR;
                if (w < 30 && (unsigned)dw < (unsigned)PD) {
                    float c = ((float)s11[rr] +
                               (float)(s12[rr] + s21[rr]) * (1.0f / 254.0f) +
                               (float)s22[rr] * (1.0f / 64516.0f)) * (1.0f / 16129.0f);
                    corr[w * CSTRIDE + dh * PD + dw] = c;
                }
            }
        }
    }
    __syncthreads();

    // per-pixel softmax over 625 offsets (zeros present for OOB offsets)
    for (int w = wid; w < WW; w += 16) {
        float m = 0.f;
        for (int i = lane; i < PP; i += 64) m = fmaxf(m, corr[w * CSTRIDE + i]);
        m = fmaxf(m, __shfl_xor(m, 1));
        m = fmaxf(m, __shfl_xor(m, 2));
        m = fmaxf(m, __shfl_xor(m, 4));
        m = fmaxf(m, __shfl_xor(m, 8));
        m = fmaxf(m, __shfl_xor(m, 16));
        m = fmaxf(m, __shfl_xor(m, 32));
        float s = 0.f;
        for (int i = lane; i < PP; i += 64) {
            float e = __expf(512.f * (corr[w * CSTRIDE + i] - m));
            s += e;
            corr[w * CSTRIDE + i] = e;  // cache exp for write phase
        }
        s += __shfl_xor(s, 1);
        s += __shfl_xor(s, 2);
        s += __shfl_xor(s, 4);
        s += __shfl_xor(s, 8);
        s += __shfl_xor(s, 16);
        s += __shfl_xor(s, 32);
        if (lane == 0) is_lds[w] = 1.0f / s;
    }
    __syncthreads();

    // masked write: out[bt][i=dh*25+dw][h][w]
    float* obase = out + (size_t)bt * PP * HWD + h * WW;
    for (int idx = tid; idx < PP * WW; idx += 1024) {
        int i = idx / 30;
        int w = idx - i * 30;
        int dh = i / 25, dw = i - dh * 25;
        bool valid = ((unsigned)(h + dh - RR) < (unsigned)HH) &&
                     ((unsigned)(w + dw - RR) < (unsigned)WW);
        float val = -1.0f;
        if (valid) val = corr[w * CSTRIDE + i] * is_lds[w];
        obase[(size_t)i * HWD + w] = val;
    }
}

extern "C" void kernel_launch(void* const* d_in, const int* in_sizes, int n_in,
                              void* d_out, int out_size, void* d_ws, size_t ws_size,
                              hipStream_t stream) {
    const float* feat1 = (const float*)d_in[0];  // video [8,512,4,30,30]
    const float* feat2 = (const float*)d_in[1];  // patch [8,512,30,30]
    float* out = (float*)d_out;
    unsigned char* Apk = (unsigned char*)d_ws;                   // [8*30][32 KB]
    unsigned char* Bpk = Apk + (size_t)BD * 30 * ROWPKB;         // [32*30][32 KB]

    norm_pack_kernel<<<dim3(30, 8), 256, 0, stream>>>(feat2, Apk, HWD, 1);
    norm_pack_kernel<<<dim3(30, 32), 256, 0, stream>>>(feat1, Bpk, TD * HWD, TD);
    corr_kernel<<<dim3(960), 1024, 0, stream>>>(Apk, Bpk, out);
}